// Round 6
// baseline (9974.243 us; speedup 1.0000x reference)
//
#include <hip/hip_runtime.h>
#include <cstdint>
#include <cstddef>

#define T_STEPS 2048
#define BATCH   32
#define HID     512
#define NG      2048            // 4*HID gate rows

typedef __attribute__((ext_vector_type(8))) short        s16x8;
typedef __attribute__((ext_vector_type(4))) float        f32x4;
typedef __attribute__((ext_vector_type(4))) unsigned int u32x4;
typedef unsigned int u32;

// ws layout: ctl (4 KB, at offset 0 so poison-blit dirty lines are long evicted),
// hbuf (3 slots x [32][512] bf16 = 96 KB), xp (256 MB).
#define CTL_OFF   0
#define HBUF_OFF  4096
#define SLOT_ELEMS (BATCH * HID)                 // 16384
#define HBUF_BYTES (3 * SLOT_ELEMS * 2)          // 98304
#define XP_OFF    (HBUF_OFF + HBUF_BYTES)        // 102400

__device__ __forceinline__ unsigned short f2bf(float f) {
    u32 u = __builtin_bit_cast(u32, f);
    u += 0x7FFFu + ((u >> 16) & 1u);             // RTNE
    return (unsigned short)(u >> 16);
}
__device__ __forceinline__ float bf2f(u32 h) {   // bf16 in low 16 bits
    return __builtin_bit_cast(float, h << 16);
}
__device__ __forceinline__ float sigm(float x) {
    return __fdividef(1.0f, 1.0f + __expf(-x));
}
__device__ __forceinline__ float tanhfast(float x) {
    float xc = fminf(fmaxf(x, -15.0f), 15.0f);
    float e = __expf(2.0f * xc);
    return __fdividef(e - 1.0f, e + 1.0f);
}

// Exchange ops. COH=true: same-XCD shared-L2 (sc0). COH=false: system scope
// via LLC (sc0 sc1, round-4-proven). Loads NOT ready until explicit s_waitcnt.
template<bool COH>
__device__ __forceinline__ s16x8 ex_load16(const unsigned short* p) {
    s16x8 r;
    if constexpr (COH)
        asm volatile("global_load_dwordx4 %0, %1, off sc0" : "=v"(r) : "v"(p) : "memory");
    else
        asm volatile("global_load_dwordx4 %0, %1, off sc0 sc1" : "=v"(r) : "v"(p) : "memory");
    return r;
}
template<bool COH>
__device__ __forceinline__ void ex_store4(unsigned short* p, u32 v) {
    if constexpr (COH)
        asm volatile("global_store_dword %0, %1, off sc0" :: "v"(p), "v"(v) : "memory");
    else
        asm volatile("global_store_dword %0, %1, off sc0 sc1" :: "v"(p), "v"(v) : "memory");
}
__device__ __forceinline__ u32 l2_load4(const u32* p) {   // sc0 dword load (test)
    u32 r;
    asm volatile("global_load_dword %0, %1, off sc0" : "=v"(r) : "v"(p) : "memory");
    return r;
}
__device__ __forceinline__ void l2_store4(u32* p, u32 v) { // sc0 dword store (test)
    asm volatile("global_store_dword %0, %1, off sc0" :: "v"(p), "v"(v) : "memory");
}
__device__ __forceinline__ u32 ctl_ld(const u32* p) {
    return __hip_atomic_load(p, __ATOMIC_RELAXED, __HIP_MEMORY_SCOPE_AGENT);
}

#define MFMA16 __builtin_amdgcn_mfma_f32_16x16x32_bf16

// ctl dword map: [0..7] xcc registration table (init 0xFFFFFFFF)
// [8..15] claim counters  [16] arrival  [17] fallback
// [18,19] test-write-done g0/g1  [20,21] vote-done  [22,23] verdict (init ~0)
// [24,25] hbuf-init-done  [32..95] test cells
__global__ void init_k(u32* __restrict__ ctl) {
    int i = threadIdx.x;
    if (i < 128) {
        u32 v = 0;
        if (i < 8 || i == 22 || i == 23) v = 0xFFFFFFFFu;
        __hip_atomic_store(&ctl[i], v, __ATOMIC_RELAXED, __HIP_MEMORY_SCOPE_AGENT);
    }
}

// ---------------- xproj: xp[t][g][b] = (x @ Wih^T)[t][b][g] + bih[g] + bhh[g] ----
// grid = 512 WGs x 256 thr: 32 gate-blocks (64 gates) x 16 t-chunks (128 t each).
// Register-prefetch double-buffered staging.
__launch_bounds__(256, 1)
__global__ void xproj_k(const float* __restrict__ x, const float* __restrict__ Wih,
                        const float* __restrict__ bih, const float* __restrict__ bhh,
                        unsigned short* __restrict__ xp) {
    const int tid = threadIdx.x, lane = tid & 63, wv = tid >> 6;
    const int gblk = blockIdx.x & 31, tch = blockIdx.x >> 5;
    const int g0 = gblk * 64 + wv * 16;
    const int jr = lane & 15, kq = lane >> 4;

    __shared__ unsigned short xs[32][520];

    s16x8 aw[16];
    #pragma unroll
    for (int kf = 0; kf < 16; ++kf) {
        const float* s = Wih + (size_t)(g0 + jr) * 512 + kf * 32 + kq * 8;
        f32x4 v0 = *(const f32x4*)s, v1 = *(const f32x4*)(s + 4);
        s16x8 f;
        f[0]=(short)f2bf(v0[0]); f[1]=(short)f2bf(v0[1]); f[2]=(short)f2bf(v0[2]); f[3]=(short)f2bf(v0[3]);
        f[4]=(short)f2bf(v1[0]); f[5]=(short)f2bf(v1[1]); f[6]=(short)f2bf(v1[2]); f[7]=(short)f2bf(v1[3]);
        aw[kf] = f;
    }
    float bias[4];
    #pragma unroll
    for (int q = 0; q < 4; ++q) bias[q] = bih[g0 + kq*4 + q] + bhh[g0 + kq*4 + q];

    const int lb = tid & 31, lk = (tid >> 5) * 64;
    const int t0 = tch * 128, t1 = t0 + 128;

    f32x4 pre[16];
    // preload t0
    {
        const float* src = x + ((size_t)t0 * BATCH + lb) * 512 + lk;
        #pragma unroll
        for (int i = 0; i < 8; ++i) {
            pre[2*i]   = *(const f32x4*)(src + i * 8);
            pre[2*i+1] = *(const f32x4*)(src + i * 8 + 4);
        }
        #pragma unroll
        for (int i = 0; i < 8; ++i) {
            s16x8 f;
            f[0]=(short)f2bf(pre[2*i][0]);   f[1]=(short)f2bf(pre[2*i][1]);
            f[2]=(short)f2bf(pre[2*i][2]);   f[3]=(short)f2bf(pre[2*i][3]);
            f[4]=(short)f2bf(pre[2*i+1][0]); f[5]=(short)f2bf(pre[2*i+1][1]);
            f[6]=(short)f2bf(pre[2*i+1][2]); f[7]=(short)f2bf(pre[2*i+1][3]);
            *(s16x8*)&xs[lb][lk + i * 8] = f;
        }
    }
    __syncthreads();

    for (int t = t0; t < t1; ++t) {
        if (t + 1 < t1) {   // issue next tile loads (overlap MFMA)
            const float* src = x + ((size_t)(t+1) * BATCH + lb) * 512 + lk;
            #pragma unroll
            for (int i = 0; i < 8; ++i) {
                pre[2*i]   = *(const f32x4*)(src + i * 8);
                pre[2*i+1] = *(const f32x4*)(src + i * 8 + 4);
            }
        }
        f32x4 acc0 = {0,0,0,0}, acc1 = {0,0,0,0};
        #pragma unroll
        for (int kf = 0; kf < 16; ++kf) {
            s16x8 xb0 = *(const s16x8*)&xs[jr][kf * 32 + kq * 8];
            s16x8 xb1 = *(const s16x8*)&xs[16 + jr][kf * 32 + kq * 8];
            acc0 = MFMA16(aw[kf], xb0, acc0, 0, 0, 0);
            acc1 = MFMA16(aw[kf], xb1, acc1, 0, 0, 0);
        }
        #pragma unroll
        for (int q = 0; q < 4; ++q) {
            int g = g0 + kq * 4 + q;
            xp[((size_t)t * NG + g) * 32 + jr]      = f2bf(acc0[q] + bias[q]);
            xp[((size_t)t * NG + g) * 32 + 16 + jr] = f2bf(acc1[q] + bias[q]);
        }
        __syncthreads();
        if (t + 1 < t1) {
            #pragma unroll
            for (int i = 0; i < 8; ++i) {
                s16x8 f;
                f[0]=(short)f2bf(pre[2*i][0]);   f[1]=(short)f2bf(pre[2*i][1]);
                f[2]=(short)f2bf(pre[2*i][2]);   f[3]=(short)f2bf(pre[2*i][3]);
                f[4]=(short)f2bf(pre[2*i+1][0]); f[5]=(short)f2bf(pre[2*i+1][1]);
                f[6]=(short)f2bf(pre[2*i+1][2]); f[7]=(short)f2bf(pre[2*i+1][3]);
                *(s16x8*)&xs[lb][lk + i * 8] = f;
            }
        }
        __syncthreads();
    }
}

// ---------------- recurrence main loop (round-4 proven body, flavored) ------
template<bool COH>
__device__ __forceinline__ void rec_loop(
    const unsigned short* __restrict__ xp,
    unsigned short* __restrict__ hbuf,
    float* __restrict__ out,
    const s16x8 (&bw)[4][16], float (&creg)[4],
    int b0, int jr, int kq, int j16, int hoff, int stoff)
{
    s16x8 ha[16];
    {
        const unsigned short* hp = hbuf + hoff;
        #pragma unroll
        for (int kf = 0; kf < 16; ++kf) ha[kf] = ex_load16<COH>(hp + kf * 32);
    }
    uint2 xv0, xv1, xv2, xv3;
    {
        const unsigned short* xq = xp;
        xv0 = *(const uint2*)(xq + ((size_t)(0 * 512 + j16)) * 32 + b0 + kq * 4);
        xv1 = *(const uint2*)(xq + ((size_t)(1 * 512 + j16)) * 32 + b0 + kq * 4);
        xv2 = *(const uint2*)(xq + ((size_t)(2 * 512 + j16)) * 32 + b0 + kq * 4);
        xv3 = *(const uint2*)(xq + ((size_t)(3 * 512 + j16)) * 32 + b0 + kq * 4);
    }

    for (int t = 0; t < T_STEPS; ++t) {
        const int s0 = t % 3, s1 = (t + 1) % 3, s2 = (t + 2) % 3;

        asm volatile("s_waitcnt vmcnt(4)" ::: "memory");   // h loads landed
        __builtin_amdgcn_sched_barrier(0);
        while (true) {
            u32 mx = 0;
            #pragma unroll
            for (int kf = 0; kf < 16; ++kf) {
                u32x4 d = __builtin_bit_cast(u32x4, ha[kf]);
                u32 a = d[0] > d[1] ? d[0] : d[1];
                u32 b = d[2] > d[3] ? d[2] : d[3];
                u32 c = a > b ? a : b;
                mx = mx > c ? mx : c;
            }
            if (!__any(mx == 0xFFFFFFFFu)) break;
            const unsigned short* hp = hbuf + s0 * SLOT_ELEMS + hoff;
            #pragma unroll
            for (int kf = 0; kf < 16; ++kf) ha[kf] = ex_load16<COH>(hp + kf * 32);
            asm volatile("s_waitcnt vmcnt(0)" ::: "memory");
            __builtin_amdgcn_sched_barrier(0);
        }
        asm volatile("s_waitcnt vmcnt(0)" ::: "memory");   // drain xp prefetch
        __builtin_amdgcn_sched_barrier(0);

        // sentinel-restore slot s2 (safe: slot s0 full => s2 fully consumed)
        {
            unsigned short* rp = hbuf + s2 * SLOT_ELEMS + stoff;
            ex_store4<COH>(rp, 0xFFFFFFFFu);
            ex_store4<COH>(rp + HID, 0xFFFFFFFFu);
        }

        f32x4 acc[4];
        acc[0][0]=bf2f(xv0.x&0xFFFFu); acc[0][1]=bf2f(xv0.x>>16); acc[0][2]=bf2f(xv0.y&0xFFFFu); acc[0][3]=bf2f(xv0.y>>16);
        acc[1][0]=bf2f(xv1.x&0xFFFFu); acc[1][1]=bf2f(xv1.x>>16); acc[1][2]=bf2f(xv1.y&0xFFFFu); acc[1][3]=bf2f(xv1.y>>16);
        acc[2][0]=bf2f(xv2.x&0xFFFFu); acc[2][1]=bf2f(xv2.x>>16); acc[2][2]=bf2f(xv2.y&0xFFFFu); acc[2][3]=bf2f(xv2.y>>16);
        acc[3][0]=bf2f(xv3.x&0xFFFFu); acc[3][1]=bf2f(xv3.x>>16); acc[3][2]=bf2f(xv3.y&0xFFFFu); acc[3][3]=bf2f(xv3.y>>16);
        #pragma unroll
        for (int kf = 0; kf < 16; ++kf) {
            acc[0] = MFMA16(ha[kf], bw[0][kf], acc[0], 0, 0, 0);
            acc[1] = MFMA16(ha[kf], bw[1][kf], acc[1], 0, 0, 0);
            acc[2] = MFMA16(ha[kf], bw[2][kf], acc[2], 0, 0, 0);
            acc[3] = MFMA16(ha[kf], bw[3][kf], acc[3], 0, 0, 0);
        }

        float hv[4];
        #pragma unroll
        for (int q = 0; q < 4; ++q) {
            float ig = sigm(acc[0][q]);
            float fg = sigm(acc[1][q]);
            float gg = tanhfast(acc[2][q]);
            float og = sigm(acc[3][q]);
            creg[q] = fg * creg[q] + ig * gg;
            hv[q] = og * tanhfast(creg[q]);
        }

        // publish h_{t+1} (fire-and-forget; ordering vs restore handled by the
        // next iteration's entry waitcnt on the same addresses)
        {
            float p0 = __shfl_xor(hv[0], 1), p1 = __shfl_xor(hv[1], 1);
            float p2 = __shfl_xor(hv[2], 1), p3 = __shfl_xor(hv[3], 1);
            bool odd = (jr & 1);
            u32 pk0 = (u32)f2bf(odd ? p0 : hv[0]) | ((u32)f2bf(odd ? hv[0] : p0) << 16);
            u32 pk1 = (u32)f2bf(odd ? p1 : hv[1]) | ((u32)f2bf(odd ? hv[1] : p1) << 16);
            u32 pk2 = (u32)f2bf(odd ? p2 : hv[2]) | ((u32)f2bf(odd ? hv[2] : p2) << 16);
            u32 pk3 = (u32)f2bf(odd ? p3 : hv[3]) | ((u32)f2bf(odd ? hv[3] : p3) << 16);
            unsigned short* sp = hbuf + s1 * SLOT_ELEMS + stoff;
            ex_store4<COH>(sp,       odd ? pk2 : pk0);
            ex_store4<COH>(sp + HID, odd ? pk3 : pk1);
        }

        #pragma unroll
        for (int q = 0; q < 4; ++q)
            out[((size_t)t * BATCH + b0 + kq * 4 + q) * HID + j16] = hv[q];

        if (t == T_STEPS - 1) {
            #pragma unroll
            for (int q = 0; q < 4; ++q) {
                out[(size_t)T_STEPS * BATCH * HID + (size_t)(b0 + kq*4 + q) * HID + j16] = hv[q];
                out[(size_t)T_STEPS * BATCH * HID + BATCH * HID
                    + (size_t)(b0 + kq*4 + q) * HID + j16] = creg[q];
            }
        } else {
            const unsigned short* hp = hbuf + s1 * SLOT_ELEMS + hoff;
            #pragma unroll
            for (int kf = 0; kf < 16; ++kf) ha[kf] = ex_load16<COH>(hp + kf * 32);
            const unsigned short* xq = xp + (size_t)(t + 1) * NG * 32;
            xv0 = *(const uint2*)(xq + ((size_t)(0 * 512 + j16)) * 32 + b0 + kq * 4);
            xv1 = *(const uint2*)(xq + ((size_t)(1 * 512 + j16)) * 32 + b0 + kq * 4);
            xv2 = *(const uint2*)(xq + ((size_t)(2 * 512 + j16)) * 32 + b0 + kq * 4);
            xv3 = *(const uint2*)(xq + ((size_t)(3 * 512 + j16)) * 32 + b0 + kq * 4);
        }
    }
}

// ---------------- persistent recurrence with VERIFIED XCD-local promotion ----
__launch_bounds__(64, 1)
__global__ void rec_k(const unsigned short* __restrict__ xp,
                      const float* __restrict__ Whh,
                      const float* __restrict__ h0,
                      const float* __restrict__ c0,
                      unsigned short* __restrict__ hbuf,
                      u32* __restrict__ ctl,
                      float* __restrict__ out) {
    const int lane = threadIdx.x & 63;

    // ---- register this WG's XCD identity (value-based, no field assumptions) ----
    u32 raw;
    asm volatile("s_getreg_b32 %0, hwreg(HW_REG_XCC_ID)" : "=s"(raw));
    u32 key = (raw == 0xFFFFFFFFu) ? 0x7E57C0DEu : raw;

    int idx = -1; u32 my = 0xFFFFu;
    if (lane == 0) {
        for (int i = 0; i < 8; ++i) {
            u32 old = atomicCAS(&ctl[i], 0xFFFFFFFFu, key);
            if (old == 0xFFFFFFFFu || old == key) { idx = i; break; }
        }
        if (idx >= 0) my = atomicAdd(&ctl[8 + idx], 1u);
    }
    idx = __shfl(idx, 0);
    my  = (u32)__shfl((int)my, 0);

    // ---- arrival barrier (all 256 single-wave WGs are co-resident) ----
    if (lane == 0) atomicAdd(&ctl[16], 1u);
    while (ctl_ld(&ctl[16]) < 256u) __builtin_amdgcn_s_sleep(2);

    u32 c0n = ctl_ld(&ctl[8]), c1n = ctl_ld(&ctl[9]);
    u32 n0 = c0n < 32u ? c0n : 32u;
    u32 n1 = c1n < 32u ? c1n : 32u;

    int role;
    const bool native = (idx == 0 || idx == 1) && (my < 32u);
    if (native) {
        role = idx * 32 + (int)my;
    } else {
        u32 fb = 0;
        if (lane == 0) fb = atomicAdd(&ctl[17], 1u);
        fb = (u32)__shfl((int)fb, 0);
        u32 m0 = 32 - n0, m1 = 32 - n1;
        if (fb < m0)            role = (int)(n0 + fb);
        else if (fb < m0 + m1)  role = (int)(32 + n1 + (fb - m0));
        else { __builtin_amdgcn_fence(__ATOMIC_ACQ_REL, "agent"); return; }
    }
    const int g = role >> 5;

    // ---- coherence self-test for the candidate sc0/L2 flavor ----
    u32* tst = ctl + 32;
    if (lane == 0) l2_store4(&tst[role], 0xC0DE0000u | (u32)role);
    asm volatile("s_waitcnt vmcnt(0)" ::: "memory");
    if (lane == 0) atomicAdd(&ctl[18 + g], 1u);
    while (ctl_ld(&ctl[18 + g]) < 32u) __builtin_amdgcn_s_sleep(1);

    u32 got = 0;
    if (lane < 32) got = l2_load4(&tst[g * 32 + lane]);
    asm volatile("s_waitcnt vmcnt(0)" ::: "memory");
    bool ok = __all(lane < 32 ? (got == (0xC0DE0000u | (u32)(g * 32 + lane))) : 1);
    if (lane == 0 && !ok) atomicAnd(&ctl[22 + g], 0u);
    if (lane == 0) atomicAdd(&ctl[20 + g], 1u);
    while (ctl_ld(&ctl[20 + g]) < 32u) __builtin_amdgcn_s_sleep(1);
    const bool coh = (ctl_ld(&ctl[22 + g]) == 0xFFFFFFFFu);

    // ---- geometry ----
    const int w   = role & 31;
    const int b0  = g * 16;
    const int jr  = lane & 15, kq = lane >> 4;
    const int j16 = w * 16 + jr;
    const int hoff  = (b0 + jr) * HID + kq * 8;
    const int qa    = (jr & 1) * 2;
    const int bq    = b0 + kq * 4 + qa;
    const int je    = w * 16 + (jr & ~1);
    const int stoff = bq * HID + je;

    // ---- owner-init of this wave's exchange tile (same flavor as protocol) ----
    {
        u32 h00 = (u32)f2bf(h0[(size_t)bq * HID + je])
                | ((u32)f2bf(h0[(size_t)bq * HID + je + 1]) << 16);
        u32 h01 = (u32)f2bf(h0[(size_t)(bq + 1) * HID + je])
                | ((u32)f2bf(h0[(size_t)(bq + 1) * HID + je + 1]) << 16);
        if (coh) {
            ex_store4<true>(hbuf + stoff, h00);
            ex_store4<true>(hbuf + stoff + HID, h01);
            ex_store4<true>(hbuf + 1 * SLOT_ELEMS + stoff, 0xFFFFFFFFu);
            ex_store4<true>(hbuf + 1 * SLOT_ELEMS + stoff + HID, 0xFFFFFFFFu);
            ex_store4<true>(hbuf + 2 * SLOT_ELEMS + stoff, 0xFFFFFFFFu);
            ex_store4<true>(hbuf + 2 * SLOT_ELEMS + stoff + HID, 0xFFFFFFFFu);
        } else {
            ex_store4<false>(hbuf + stoff, h00);
            ex_store4<false>(hbuf + stoff + HID, h01);
            ex_store4<false>(hbuf + 1 * SLOT_ELEMS + stoff, 0xFFFFFFFFu);
            ex_store4<false>(hbuf + 1 * SLOT_ELEMS + stoff + HID, 0xFFFFFFFFu);
            ex_store4<false>(hbuf + 2 * SLOT_ELEMS + stoff, 0xFFFFFFFFu);
            ex_store4<false>(hbuf + 2 * SLOT_ELEMS + stoff + HID, 0xFFFFFFFFu);
        }
        asm volatile("s_waitcnt vmcnt(0)" ::: "memory");
        if (lane == 0) atomicAdd(&ctl[24 + g], 1u);
        while (ctl_ld(&ctl[24 + g]) < 32u) __builtin_amdgcn_s_sleep(1);
    }

    // ---- weights + cell state ----
    s16x8 bw[4][16];
    #pragma unroll
    for (int cf = 0; cf < 4; ++cf) {
        #pragma unroll
        for (int kf = 0; kf < 16; ++kf) {
            const float* s = Whh + (size_t)(cf * 512 + j16) * 512 + kf * 32 + kq * 8;
            f32x4 v0 = *(const f32x4*)s, v1 = *(const f32x4*)(s + 4);
            s16x8 f;
            f[0]=(short)f2bf(v0[0]); f[1]=(short)f2bf(v0[1]); f[2]=(short)f2bf(v0[2]); f[3]=(short)f2bf(v0[3]);
            f[4]=(short)f2bf(v1[0]); f[5]=(short)f2bf(v1[1]); f[6]=(short)f2bf(v1[2]); f[7]=(short)f2bf(v1[3]);
            bw[cf][kf] = f;
        }
    }
    float creg[4];
    #pragma unroll
    for (int q = 0; q < 4; ++q)
        creg[q] = c0[(size_t)(b0 + kq * 4 + q) * HID + j16];

    if (coh) rec_loop<true >(xp, hbuf, out, bw, creg, b0, jr, kq, j16, hoff, stoff);
    else     rec_loop<false>(xp, hbuf, out, bw, creg, b0, jr, kq, j16, hoff, stoff);

    // ---- replay hygiene: write back + invalidate this XCD's L2 ----
    __builtin_amdgcn_fence(__ATOMIC_ACQ_REL, "agent");
}

extern "C" void kernel_launch(void* const* d_in, const int* in_sizes, int n_in,
                              void* d_out, int out_size, void* d_ws, size_t ws_size,
                              hipStream_t stream) {
    const float* x   = (const float*)d_in[0];
    const float* h0  = (const float*)d_in[1];
    const float* c0  = (const float*)d_in[2];
    const float* Wih = (const float*)d_in[3];
    const float* Whh = (const float*)d_in[4];
    const float* bih = (const float*)d_in[5];
    const float* bhh = (const float*)d_in[6];
    float* out = (float*)d_out;

    char* ws = (char*)d_ws;
    u32*            ctl  = (u32*)(ws + CTL_OFF);
    unsigned short* hbuf = (unsigned short*)(ws + HBUF_OFF);
    unsigned short* xp   = (unsigned short*)(ws + XP_OFF);

    init_k<<<dim3(1), dim3(256), 0, stream>>>(ctl);
    xproj_k<<<dim3(512), dim3(256), 0, stream>>>(x, Wih, bih, bhh, xp);
    rec_k<<<dim3(256), dim3(64), 0, stream>>>(xp, Whh, h0, c0, hbuf, ctl, out);
}

// Round 8
// 9638.173 us; speedup vs baseline: 1.0349x; 1.0349x over previous
//
#include <hip/hip_runtime.h>
#include <cstdint>
#include <cstddef>

#define T_STEPS 2048
#define BATCH   32
#define HID     512
#define NG      2048            // 4*HID gate rows

typedef __attribute__((ext_vector_type(8))) short        s16x8;
typedef __attribute__((ext_vector_type(4))) float        f32x4;
typedef __attribute__((ext_vector_type(4))) unsigned int u32x4;
typedef unsigned int u32;

// ws layout: hbuf (3 slots x [32][512] bf16 = 96 KB, 4KB-aligned), xp (256 MB)
#define SLOT_ELEMS (BATCH * HID)                 // 16384
#define HBUF_OFF   0
#define XP_OFF     (3 * SLOT_ELEMS * 2 + 4096)   // 102400
#define SENT 0xFFFFFFFFu

__device__ __forceinline__ unsigned short f2bf(float f) {
    u32 u = __builtin_bit_cast(u32, f);
    u += 0x7FFFu + ((u >> 16) & 1u);             // RTNE
    return (unsigned short)(u >> 16);
}
__device__ __forceinline__ float bf2f(u32 h) {   // bf16 in low 16 bits
    return __builtin_bit_cast(float, h << 16);
}
__device__ __forceinline__ float sigm(float x) {
    return __fdividef(1.0f, 1.0f + __expf(-x));
}
__device__ __forceinline__ float tanhfast(float x) {
    float xc = fminf(fmaxf(x, -15.0f), 15.0f);
    float e = __expf(2.0f * xc);
    return __fdividef(e - 1.0f, e + 1.0f);
}

// System-coherent exchange ops (LLC is the coherence point; proven r2-r6).
// Loads are NOT ready until an explicit s_waitcnt vmcnt.
__device__ __forceinline__ u32x4 llc_load16(const unsigned short* p) {
    u32x4 r;
    asm volatile("global_load_dwordx4 %0, %1, off sc0 sc1" : "=v"(r) : "v"(p) : "memory");
    return r;
}
__device__ __forceinline__ void llc_store4(unsigned short* p, u32 v) {
    asm volatile("global_store_dword %0, %1, off sc0 sc1" :: "v"(p), "v"(v) : "memory");
}

#define MFMA16 __builtin_amdgcn_mfma_f32_16x16x32_bf16

// ---------------- init: slot0 = h0 (bf16), slots 1,2 = sentinel ----------------
__global__ void init_k(const float* __restrict__ h0, unsigned short* __restrict__ hb) {
    int idx = blockIdx.x * 256 + threadIdx.x;          // grid 192 -> 49152
    if (idx < SLOT_ELEMS) hb[idx] = f2bf(h0[idx]);
    else                  hb[idx] = 0xFFFFu;           // sentinel halves
}

// ---------------- xproj: xp[t][g][b] = (x @ Wih^T)[t][b][g] + bih[g] + bhh[g] ----
// grid = 512 WGs x 256 thr: 32 gate-blocks x 16 t-chunks, reg-prefetch dbuf.
__launch_bounds__(256, 1)
__global__ void xproj_k(const float* __restrict__ x, const float* __restrict__ Wih,
                        const float* __restrict__ bih, const float* __restrict__ bhh,
                        unsigned short* __restrict__ xp) {
    const int tid = threadIdx.x, lane = tid & 63, wv = tid >> 6;
    const int gblk = blockIdx.x & 31, tch = blockIdx.x >> 5;
    const int g0 = gblk * 64 + wv * 16;
    const int jr = lane & 15, kq = lane >> 4;

    __shared__ unsigned short xs[32][520];

    s16x8 aw[16];
    #pragma unroll
    for (int kf = 0; kf < 16; ++kf) {
        const float* s = Wih + (size_t)(g0 + jr) * 512 + kf * 32 + kq * 8;
        f32x4 v0 = *(const f32x4*)s, v1 = *(const f32x4*)(s + 4);
        s16x8 f;
        f[0]=(short)f2bf(v0[0]); f[1]=(short)f2bf(v0[1]); f[2]=(short)f2bf(v0[2]); f[3]=(short)f2bf(v0[3]);
        f[4]=(short)f2bf(v1[0]); f[5]=(short)f2bf(v1[1]); f[6]=(short)f2bf(v1[2]); f[7]=(short)f2bf(v1[3]);
        aw[kf] = f;
    }
    float bias[4];
    #pragma unroll
    for (int q = 0; q < 4; ++q) bias[q] = bih[g0 + kq*4 + q] + bhh[g0 + kq*4 + q];

    const int lb = tid & 31, lk = (tid >> 5) * 64;
    const int t0 = tch * 128, t1 = t0 + 128;

    f32x4 pre[16];
    {
        const float* src = x + ((size_t)t0 * BATCH + lb) * 512 + lk;
        #pragma unroll
        for (int i = 0; i < 8; ++i) {
            pre[2*i]   = *(const f32x4*)(src + i * 8);
            pre[2*i+1] = *(const f32x4*)(src + i * 8 + 4);
        }
        #pragma unroll
        for (int i = 0; i < 8; ++i) {
            s16x8 f;
            f[0]=(short)f2bf(pre[2*i][0]);   f[1]=(short)f2bf(pre[2*i][1]);
            f[2]=(short)f2bf(pre[2*i][2]);   f[3]=(short)f2bf(pre[2*i][3]);
            f[4]=(short)f2bf(pre[2*i+1][0]); f[5]=(short)f2bf(pre[2*i+1][1]);
            f[6]=(short)f2bf(pre[2*i+1][2]); f[7]=(short)f2bf(pre[2*i+1][3]);
            *(s16x8*)&xs[lb][lk + i * 8] = f;
        }
    }
    __syncthreads();

    for (int t = t0; t < t1; ++t) {
        if (t + 1 < t1) {
            const float* src = x + ((size_t)(t+1) * BATCH + lb) * 512 + lk;
            #pragma unroll
            for (int i = 0; i < 8; ++i) {
                pre[2*i]   = *(const f32x4*)(src + i * 8);
                pre[2*i+1] = *(const f32x4*)(src + i * 8 + 4);
            }
        }
        f32x4 acc0 = {0,0,0,0}, acc1 = {0,0,0,0};
        #pragma unroll
        for (int kf = 0; kf < 16; ++kf) {
            s16x8 xb0 = *(const s16x8*)&xs[jr][kf * 32 + kq * 8];
            s16x8 xb1 = *(const s16x8*)&xs[16 + jr][kf * 32 + kq * 8];
            acc0 = MFMA16(aw[kf], xb0, acc0, 0, 0, 0);
            acc1 = MFMA16(aw[kf], xb1, acc1, 0, 0, 0);
        }
        #pragma unroll
        for (int q = 0; q < 4; ++q) {
            int g = g0 + kq * 4 + q;
            xp[((size_t)t * NG + g) * 32 + jr]      = f2bf(acc0[q] + bias[q]);
            xp[((size_t)t * NG + g) * 32 + 16 + jr] = f2bf(acc1[q] + bias[q]);
        }
        __syncthreads();
        if (t + 1 < t1) {
            #pragma unroll
            for (int i = 0; i < 8; ++i) {
                s16x8 f;
                f[0]=(short)f2bf(pre[2*i][0]);   f[1]=(short)f2bf(pre[2*i][1]);
                f[2]=(short)f2bf(pre[2*i][2]);   f[3]=(short)f2bf(pre[2*i][3]);
                f[4]=(short)f2bf(pre[2*i+1][0]); f[5]=(short)f2bf(pre[2*i+1][1]);
                f[6]=(short)f2bf(pre[2*i+1][2]); f[7]=(short)f2bf(pre[2*i+1][3]);
                *(s16x8*)&xs[lb][lk + i * 8] = f;
            }
        }
        __syncthreads();
    }
}

// ---------------- persistent recurrence: 16 WGs x 256 thr (4 waves) ----------
// WG = (group g: 16 batches) x (64-hid block w64). Wave v owns 16 hid x 4 gates
// (identical per-wave geometry to the round-4-verified kernel). h flows:
//   publish own 2KB quarter -> global (sc0sc1, write-through)
//   stage foreign 14KB -> LDS (per-thread 16B sentinel-retry), own -> LDS direct
//   all 4 waves read A-frags from LDS (amortizes the h read 4x, cuts global
//   exchange volume 32 consumers -> 8 per group).
__launch_bounds__(256, 1)
__global__ void rec_k(const unsigned short* __restrict__ xp,
                      const float* __restrict__ Whh,
                      const float* __restrict__ c0,
                      unsigned short* __restrict__ hbuf,   // [3][32][512] bf16
                      float* __restrict__ out) {
    const int tid = threadIdx.x, lane = tid & 63, wv = tid >> 6;
    const int g   = blockIdx.x >> 3;      // group 0..1
    const int w64 = blockIdx.x & 7;       // 64-hid block 0..7
    const int b0  = g * 16;
    const int jr  = lane & 15, kq = lane >> 4;
    const int j0  = w64 * 64 + wv * 16;
    const int j16 = j0 + jr;

    __shared__ unsigned short hlds[2][16][520];   // [buf][batch][hid+pad]

    // ---- weights: Whh rows cf*512 + j16, K=512 -> 4x16 b-frags (256 VGPR) ----
    s16x8 bw[4][16];
    #pragma unroll
    for (int cf = 0; cf < 4; ++cf) {
        #pragma unroll
        for (int kf = 0; kf < 16; ++kf) {
            const float* s = Whh + (size_t)(cf * 512 + j16) * 512 + kf * 32 + kq * 8;
            f32x4 v0 = *(const f32x4*)s, v1 = *(const f32x4*)(s + 4);
            s16x8 f;
            f[0]=(short)f2bf(v0[0]); f[1]=(short)f2bf(v0[1]); f[2]=(short)f2bf(v0[2]); f[3]=(short)f2bf(v0[3]);
            f[4]=(short)f2bf(v1[0]); f[5]=(short)f2bf(v1[1]); f[6]=(short)f2bf(v1[2]); f[7]=(short)f2bf(v1[3]);
            bw[cf][kf] = f;
        }
    }

    float creg[4];
    #pragma unroll
    for (int q = 0; q < 4; ++q)
        creg[q] = c0[(size_t)(b0 + kq * 4 + q) * HID + j16];

    // ---- publish / restore geometry (same packing as round 4) ----
    const int qa    = (jr & 1) * 2;
    const int bq    = b0 + kq * 4 + qa;
    const int je    = j0 + (jr & ~1);
    const int stoff = bq * HID + je;                  // elem offset within slot

    // ---- foreign staging chunk map (loop-invariant): 896 16B chunks ----
    const int nc = (tid < 128) ? 4 : 3;               // wave-uniform (waves 0,1 vs 2,3)
    int coff[4], loff[4];
    #pragma unroll
    for (int i = 0; i < 4; ++i) {
        int c = tid + i * 256;                        // i=3 valid only for tid<128
        int batch = c & 15, col8 = c >> 4;
        int hid8 = col8 + (col8 >= w64 * 8 ? 8 : 0);  // skip own 64-hid block
        coff[i] = (b0 + batch) * HID + hid8 * 8;
        loff[i] = batch * 1040 + hid8 * 16;           // bytes in hlds buf
    }

    // ---- prologue: full-stage slot0 (h0, no sentinels) into buf 0 ----
    {
        u32x4 st[4];
        #pragma unroll
        for (int i = 0; i < 4; ++i) {
            int c = tid + i * 256;                    // 1024 chunks = full slot
            int batch = c & 15, hid8 = c >> 4;
            st[i] = llc_load16(hbuf + (b0 + batch) * HID + hid8 * 8);
        }
        asm volatile("s_waitcnt vmcnt(0)" ::: "memory");
        __builtin_amdgcn_sched_barrier(0);
        #pragma unroll
        for (int i = 0; i < 4; ++i) {
            int c = tid + i * 256;
            int batch = c & 15, hid8 = c >> 4;
            *(u32x4*)((char*)&hlds[0][0][0] + batch * 1040 + hid8 * 16) = st[i];
        }
    }
    // xp prefetch t=0
    uint2 xv0, xv1, xv2, xv3;
    {
        const unsigned short* xq = xp;
        xv0 = *(const uint2*)(xq + ((size_t)(0 * 512 + j16)) * 32 + b0 + kq * 4);
        xv1 = *(const uint2*)(xq + ((size_t)(1 * 512 + j16)) * 32 + b0 + kq * 4);
        xv2 = *(const uint2*)(xq + ((size_t)(2 * 512 + j16)) * 32 + b0 + kq * 4);
        xv3 = *(const uint2*)(xq + ((size_t)(3 * 512 + j16)) * 32 + b0 + kq * 4);
    }
    __syncthreads();

    for (int t = 0; t < T_STEPS; ++t) {
        const int cur = t & 1, nxt = cur ^ 1;
        const int s1 = (t + 1) % 3, s2 = (t + 2) % 3;

        // ---- issue sentinel-restore of slot s2 early (own cells; provably dead:
        //      we entered step t => all WGs published s0 => s2 fully consumed) ----
        {
            unsigned short* rp = hbuf + s2 * SLOT_ELEMS + stoff;
            llc_store4(rp, SENT);
            llc_store4(rp + HID, SENT);
        }

        // ---- gates = xp + h @ Whh^T, A-frags streamed from LDS ----
        f32x4 acc[4];
        acc[0][0]=bf2f(xv0.x&0xFFFFu); acc[0][1]=bf2f(xv0.x>>16); acc[0][2]=bf2f(xv0.y&0xFFFFu); acc[0][3]=bf2f(xv0.y>>16);
        acc[1][0]=bf2f(xv1.x&0xFFFFu); acc[1][1]=bf2f(xv1.x>>16); acc[1][2]=bf2f(xv1.y&0xFFFFu); acc[1][3]=bf2f(xv1.y>>16);
        acc[2][0]=bf2f(xv2.x&0xFFFFu); acc[2][1]=bf2f(xv2.x>>16); acc[2][2]=bf2f(xv2.y&0xFFFFu); acc[2][3]=bf2f(xv2.y>>16);
        acc[3][0]=bf2f(xv3.x&0xFFFFu); acc[3][1]=bf2f(xv3.x>>16); acc[3][2]=bf2f(xv3.y&0xFFFFu); acc[3][3]=bf2f(xv3.y>>16);
        #pragma unroll
        for (int kf = 0; kf < 16; ++kf) {
            s16x8 h8 = *(const s16x8*)((const char*)&hlds[0][0][0]
                         + cur * (16 * 1040) + jr * 1040 + kf * 64 + kq * 16);
            acc[0] = MFMA16(h8, bw[0][kf], acc[0], 0, 0, 0);
            acc[1] = MFMA16(h8, bw[1][kf], acc[1], 0, 0, 0);
            acc[2] = MFMA16(h8, bw[2][kf], acc[2], 0, 0, 0);
            acc[3] = MFMA16(h8, bw[3][kf], acc[3], 0, 0, 0);
        }

        // ---- cell update fully in-register (single correct pass) ----
        float hv[4];
        #pragma unroll
        for (int q = 0; q < 4; ++q) {
            float ig = sigm(acc[0][q]);
            float fg = sigm(acc[1][q]);
            float gg = tanhfast(acc[2][q]);
            float og = sigm(acc[3][q]);
            creg[q] = fg * creg[q] + ig * gg;
            hv[q] = og * tanhfast(creg[q]);
        }

        // ---- drain restore (orders restore(s2) before publish(s1)), publish ----
        asm volatile("s_waitcnt vmcnt(0)" ::: "memory");
        u32 w0, w1;
        {
            float p0 = __shfl_xor(hv[0], 1), p1 = __shfl_xor(hv[1], 1);
            float p2 = __shfl_xor(hv[2], 1), p3 = __shfl_xor(hv[3], 1);
            bool odd = (jr & 1);
            u32 pk0 = (u32)f2bf(odd ? p0 : hv[0]) | ((u32)f2bf(odd ? hv[0] : p0) << 16);
            u32 pk1 = (u32)f2bf(odd ? p1 : hv[1]) | ((u32)f2bf(odd ? hv[1] : p1) << 16);
            u32 pk2 = (u32)f2bf(odd ? p2 : hv[2]) | ((u32)f2bf(odd ? hv[2] : p2) << 16);
            u32 pk3 = (u32)f2bf(odd ? p3 : hv[3]) | ((u32)f2bf(odd ? hv[3] : p3) << 16);
            w0 = odd ? pk2 : pk0;
            w1 = odd ? pk3 : pk1;
            unsigned short* sp = hbuf + s1 * SLOT_ELEMS + stoff;
            llc_store4(sp, w0);
            llc_store4(sp + HID, w1);
        }
        // own quarter -> LDS next buffer (no global RT for self)
        {
            char* lb = (char*)&hlds[0][0][0] + nxt * (16 * 1040);
            *(u32*)(lb + (kq * 4 + qa) * 1040 + je * 2)     = w0;
            *(u32*)(lb + (kq * 4 + qa + 1) * 1040 + je * 2) = w1;
        }

        u32x4 st[4];
        if (t + 1 < T_STEPS) {
            // issue foreign staging loads (slot s1) — latency hides under out/xp
            const unsigned short* gp = hbuf + s1 * SLOT_ELEMS;
            #pragma unroll
            for (int i = 0; i < 4; ++i) if (i < nc) st[i] = llc_load16(gp + coff[i]);
            // xp prefetch t+1 (normal cached loads)
            const unsigned short* xq = xp + (size_t)(t + 1) * NG * 32;
            xv0 = *(const uint2*)(xq + ((size_t)(0 * 512 + j16)) * 32 + b0 + kq * 4);
            xv1 = *(const uint2*)(xq + ((size_t)(1 * 512 + j16)) * 32 + b0 + kq * 4);
            xv2 = *(const uint2*)(xq + ((size_t)(2 * 512 + j16)) * 32 + b0 + kq * 4);
            xv3 = *(const uint2*)(xq + ((size_t)(3 * 512 + j16)) * 32 + b0 + kq * 4);
        }

        // ---- out stores (normal cached, off sync path) ----
        #pragma unroll
        for (int q = 0; q < 4; ++q)
            out[((size_t)t * BATCH + b0 + kq * 4 + q) * HID + j16] = hv[q];

        if (t + 1 < T_STEPS) {
            // ---- per-thread sentinel-retry, then LDS write ----
            asm volatile("s_waitcnt vmcnt(0)" ::: "memory");
            __builtin_amdgcn_sched_barrier(0);
            while (true) {
                bool dirty = false;
                #pragma unroll
                for (int i = 0; i < 4; ++i) if (i < nc) {
                    dirty |= (st[i][0] == SENT) | (st[i][1] == SENT)
                           | (st[i][2] == SENT) | (st[i][3] == SENT);
                }
                if (!__any(dirty)) break;
                if (dirty) {
                    const unsigned short* gp = hbuf + s1 * SLOT_ELEMS;
                    #pragma unroll
                    for (int i = 0; i < 4; ++i) if (i < nc) st[i] = llc_load16(gp + coff[i]);
                }
                asm volatile("s_waitcnt vmcnt(0)" ::: "memory");
                __builtin_amdgcn_sched_barrier(0);
            }
            char* lb = (char*)&hlds[0][0][0] + nxt * (16 * 1040);
            #pragma unroll
            for (int i = 0; i < 4; ++i) if (i < nc) *(u32x4*)(lb + loff[i]) = st[i];
        } else {
            // tail: h_T, c_T
            #pragma unroll
            for (int q = 0; q < 4; ++q) {
                out[(size_t)T_STEPS * BATCH * HID + (size_t)(b0 + kq*4 + q) * HID + j16] = hv[q];
                out[(size_t)T_STEPS * BATCH * HID + BATCH * HID
                    + (size_t)(b0 + kq*4 + q) * HID + j16] = creg[q];
            }
        }
        __syncthreads();
    }
}

extern "C" void kernel_launch(void* const* d_in, const int* in_sizes, int n_in,
                              void* d_out, int out_size, void* d_ws, size_t ws_size,
                              hipStream_t stream) {
    const float* x   = (const float*)d_in[0];
    const float* h0  = (const float*)d_in[1];
    const float* c0  = (const float*)d_in[2];
    const float* Wih = (const float*)d_in[3];
    const float* Whh = (const float*)d_in[4];
    const float* bih = (const float*)d_in[5];
    const float* bhh = (const float*)d_in[6];
    float* out = (float*)d_out;

    char* ws = (char*)d_ws;
    unsigned short* hbuf = (unsigned short*)(ws + HBUF_OFF);
    unsigned short* xp   = (unsigned short*)(ws + XP_OFF);

    init_k<<<dim3(192), dim3(256), 0, stream>>>(h0, hbuf);
    xproj_k<<<dim3(512), dim3(256), 0, stream>>>(x, Wih, bih, bhh, xp);
    rec_k<<<dim3(16), dim3(256), 0, stream>>>(xp, Whh, c0, hbuf, out);
}

// Round 10
// 8371.622 us; speedup vs baseline: 1.1914x; 1.1513x over previous
//
#include <hip/hip_runtime.h>
#include <cstdint>
#include <cstddef>

#define T_STEPS 2048
#define BATCH   32
#define HID     512
#define NG      2048            // 4*HID gate rows

typedef __attribute__((ext_vector_type(8))) short        s16x8;
typedef __attribute__((ext_vector_type(4))) float        f32x4;
typedef __attribute__((ext_vector_type(4))) unsigned int u32x4;
typedef __attribute__((ext_vector_type(2))) unsigned int u32x2;
typedef unsigned int u32;

// ws layout: hbuf (3 slots x [32][512] bf16 = 96 KB), xp [t][b][g] bf16 (256 MB)
#define SLOT_ELEMS (BATCH * HID)                 // 16384
#define HBUF_OFF   0
#define XP_OFF     (3 * SLOT_ELEMS * 2 + 4096)   // 102400
#define SENT 0xFFFFFFFFu

__device__ __forceinline__ unsigned short f2bf(float f) {
    u32 u = __builtin_bit_cast(u32, f);
    u += 0x7FFFu + ((u >> 16) & 1u);             // RTNE
    return (unsigned short)(u >> 16);
}
__device__ __forceinline__ float bf2f(u32 h) {   // bf16 in low 16 bits
    return __builtin_bit_cast(float, h << 16);
}
__device__ __forceinline__ float sigm(float x) {
    return __fdividef(1.0f, 1.0f + __expf(-x));
}
__device__ __forceinline__ float tanhfast(float x) {
    float xc = fminf(fmaxf(x, -15.0f), 15.0f);
    float e = __expf(2.0f * xc);
    return __fdividef(e - 1.0f, e + 1.0f);
}

// System-coherent exchange ops (LLC coherence point; r2-r8 proven live).
// Loads NOT ready until an explicit s_waitcnt vmcnt.
__device__ __forceinline__ u32x4 llc_load16(const unsigned short* p) {
    u32x4 r;
    asm volatile("global_load_dwordx4 %0, %1, off sc0 sc1" : "=v"(r) : "v"(p) : "memory");
    return r;
}
__device__ __forceinline__ void llc_store8(unsigned short* p, u32x2 v) {
    asm volatile("global_store_dwordx2 %0, %1, off sc0 sc1" :: "v"(p), "v"(v) : "memory");
}

#define MFMA16 __builtin_amdgcn_mfma_f32_16x16x32_bf16

// ---------------- init: slot0 = h0 (bf16), slots 1,2 = sentinel ----------------
__global__ void init_k(const float* __restrict__ h0, unsigned short* __restrict__ hb) {
    int idx = blockIdx.x * 256 + threadIdx.x;          // grid 192 -> 49152
    if (idx < SLOT_ELEMS) hb[idx] = f2bf(h0[idx]);
    else                  hb[idx] = 0xFFFFu;           // sentinel halves
}

// ---------------- xproj: xp[t][b][g] = (x @ Wih^T)[t][b][g] + bih[g] + bhh[g] ----
// grid = 512 WGs x 256 thr: 32 gate-blocks x 16 t-chunks, reg-prefetch dbuf.
__launch_bounds__(256, 1)
__global__ void xproj_k(const float* __restrict__ x, const float* __restrict__ Wih,
                        const float* __restrict__ bih, const float* __restrict__ bhh,
                        unsigned short* __restrict__ xp) {
    const int tid = threadIdx.x, lane = tid & 63, wv = tid >> 6;
    const int gblk = blockIdx.x & 31, tch = blockIdx.x >> 5;
    const int g0 = gblk * 64 + wv * 16;
    const int jr = lane & 15, kq = lane >> 4;

    __shared__ unsigned short xs[32][520];

    s16x8 aw[16];
    #pragma unroll
    for (int kf = 0; kf < 16; ++kf) {
        const float* s = Wih + (size_t)(g0 + jr) * 512 + kf * 32 + kq * 8;
        f32x4 v0 = *(const f32x4*)s, v1 = *(const f32x4*)(s + 4);
        s16x8 f;
        f[0]=(short)f2bf(v0[0]); f[1]=(short)f2bf(v0[1]); f[2]=(short)f2bf(v0[2]); f[3]=(short)f2bf(v0[3]);
        f[4]=(short)f2bf(v1[0]); f[5]=(short)f2bf(v1[1]); f[6]=(short)f2bf(v1[2]); f[7]=(short)f2bf(v1[3]);
        aw[kf] = f;
    }
    float bias[4];
    #pragma unroll
    for (int q = 0; q < 4; ++q) bias[q] = bih[g0 + kq*4 + q] + bhh[g0 + kq*4 + q];

    const int lb = tid & 31, lk = (tid >> 5) * 64;
    const int t0 = tch * 128, t1 = t0 + 128;

    f32x4 pre[16];
    {
        const float* src = x + ((size_t)t0 * BATCH + lb) * 512 + lk;
        #pragma unroll
        for (int i = 0; i < 8; ++i) {
            pre[2*i]   = *(const f32x4*)(src + i * 8);
            pre[2*i+1] = *(const f32x4*)(src + i * 8 + 4);
        }
        #pragma unroll
        for (int i = 0; i < 8; ++i) {
            s16x8 f;
            f[0]=(short)f2bf(pre[2*i][0]);   f[1]=(short)f2bf(pre[2*i][1]);
            f[2]=(short)f2bf(pre[2*i][2]);   f[3]=(short)f2bf(pre[2*i][3]);
            f[4]=(short)f2bf(pre[2*i+1][0]); f[5]=(short)f2bf(pre[2*i+1][1]);
            f[6]=(short)f2bf(pre[2*i+1][2]); f[7]=(short)f2bf(pre[2*i+1][3]);
            *(s16x8*)&xs[lb][lk + i * 8] = f;
        }
    }
    __syncthreads();

    for (int t = t0; t < t1; ++t) {
        if (t + 1 < t1) {
            const float* src = x + ((size_t)(t+1) * BATCH + lb) * 512 + lk;
            #pragma unroll
            for (int i = 0; i < 8; ++i) {
                pre[2*i]   = *(const f32x4*)(src + i * 8);
                pre[2*i+1] = *(const f32x4*)(src + i * 8 + 4);
            }
        }
        f32x4 acc0 = {0,0,0,0}, acc1 = {0,0,0,0};
        #pragma unroll
        for (int kf = 0; kf < 16; ++kf) {
            s16x8 xb0 = *(const s16x8*)&xs[jr][kf * 32 + kq * 8];
            s16x8 xb1 = *(const s16x8*)&xs[16 + jr][kf * 32 + kq * 8];
            acc0 = MFMA16(aw[kf], xb0, acc0, 0, 0, 0);
            acc1 = MFMA16(aw[kf], xb1, acc1, 0, 0, 0);
        }
        // D: row = gate g0+kq*4+q, col = batch jr.  Store [t][b][g] 8B-contig.
        {
            u32 a0 = (u32)f2bf(acc0[0]+bias[0]) | ((u32)f2bf(acc0[1]+bias[1]) << 16);
            u32 a1 = (u32)f2bf(acc0[2]+bias[2]) | ((u32)f2bf(acc0[3]+bias[3]) << 16);
            u32 b0p= (u32)f2bf(acc1[0]+bias[0]) | ((u32)f2bf(acc1[1]+bias[1]) << 16);
            u32 b1p= (u32)f2bf(acc1[2]+bias[2]) | ((u32)f2bf(acc1[3]+bias[3]) << 16);
            u32x2 va; va[0] = a0; va[1] = a1;
            u32x2 vb; vb[0] = b0p; vb[1] = b1p;
            *(u32x2*)&xp[((size_t)t * BATCH + jr)      * NG + g0 + kq * 4] = va;
            *(u32x2*)&xp[((size_t)t * BATCH + 16 + jr) * NG + g0 + kq * 4] = vb;
        }
        __syncthreads();
        if (t + 1 < t1) {
            #pragma unroll
            for (int i = 0; i < 8; ++i) {
                s16x8 f;
                f[0]=(short)f2bf(pre[2*i][0]);   f[1]=(short)f2bf(pre[2*i][1]);
                f[2]=(short)f2bf(pre[2*i][2]);   f[3]=(short)f2bf(pre[2*i][3]);
                f[4]=(short)f2bf(pre[2*i+1][0]); f[5]=(short)f2bf(pre[2*i+1][1]);
                f[6]=(short)f2bf(pre[2*i+1][2]); f[7]=(short)f2bf(pre[2*i+1][3]);
                *(s16x8*)&xs[lb][lk + i * 8] = f;
            }
        }
        __syncthreads();
    }
}

// ---------------- persistent recurrence: 64 WGs x 64 threads (r4 protocol) ----
// Wave = (group grp: 16 batches) x (hid block w: 16 hid x 4 gates).
// MFMA operand-swapped: acc = mfma(W, h) -> D row = weight-row, col = batch.
// Lane (jr,kq) owns batch b0+jr, hid w*16+kq*4..+4 (contiguous!): publish is
// ONE dwordx2, restore ONE dwordx2, out ONE dwordx4 -- no cross-lane shuffles
// on the ring's critical path. Consume side identical to r4.
__launch_bounds__(64, 1)
__global__ void rec_k(const unsigned short* __restrict__ xp,
                      const float* __restrict__ Whh,
                      const float* __restrict__ c0,
                      unsigned short* __restrict__ hbuf,   // [3][32][512] bf16
                      float* __restrict__ out) {
    const int lane = threadIdx.x & 63;
    const int grp  = blockIdx.x >> 5;     // 0..1
    const int w    = blockIdx.x & 31;     // hid block
    const int b0   = grp * 16;
    const int jr   = lane & 15, kq = lane >> 4;

    // B-frags -> now used as the A operand: Whh[cf*512 + w*16 + jr][k] (256 VGPR)
    s16x8 bw[4][16];
    #pragma unroll
    for (int cf = 0; cf < 4; ++cf) {
        #pragma unroll
        for (int kf = 0; kf < 16; ++kf) {
            const float* s = Whh + (size_t)(cf * 512 + w * 16 + jr) * 512 + kf * 32 + kq * 8;
            f32x4 v0 = *(const f32x4*)s, v1 = *(const f32x4*)(s + 4);
            s16x8 f;
            f[0]=(short)f2bf(v0[0]); f[1]=(short)f2bf(v0[1]); f[2]=(short)f2bf(v0[2]); f[3]=(short)f2bf(v0[3]);
            f[4]=(short)f2bf(v1[0]); f[5]=(short)f2bf(v1[1]); f[6]=(short)f2bf(v1[2]); f[7]=(short)f2bf(v1[3]);
            bw[cf][kf] = f;
        }
    }

    // cell ownership: batch b0+jr, hid he0..he0+3 (contiguous)
    const int he0 = w * 16 + kq * 4;
    float creg[4];
    {
        f32x4 c4 = *(const f32x4*)(c0 + (size_t)(b0 + jr) * HID + he0);
        creg[0]=c4[0]; creg[1]=c4[1]; creg[2]=c4[2]; creg[3]=c4[3];
    }

    const int hoff = (b0 + jr) * HID + kq * 8;   // consume-frag offset (A/B map)
    const int poff = (b0 + jr) * HID + he0;      // publish offset (8B contiguous)

    u32x4 ha[16];
    {   // prologue: h slot0 loads, then xp t=0 prefetch
        const unsigned short* hp = hbuf + hoff;
        #pragma unroll
        for (int kf = 0; kf < 16; ++kf) ha[kf] = llc_load16(hp + kf * 32);
    }
    u32x2 xv[4];
    {
        const unsigned short* xq = xp + ((size_t)0 * BATCH + b0 + jr) * NG + he0;
        #pragma unroll
        for (int cf = 0; cf < 4; ++cf) xv[cf] = *(const u32x2*)(xq + cf * 512);
    }

    for (int t = 0; t < T_STEPS; ++t) {
        const int s0 = t % 3, s1 = (t + 1) % 3, s2 = (t + 2) % 3;

        // ---- detect (r4-proven): first attempt waits h loads only ----
        asm volatile("s_waitcnt vmcnt(4)" ::: "memory");
        __builtin_amdgcn_sched_barrier(0);
        while (true) {
            u32 mx = 0;
            #pragma unroll
            for (int kf = 0; kf < 16; ++kf) {
                u32 a = ha[kf][0] > ha[kf][1] ? ha[kf][0] : ha[kf][1];
                u32 b = ha[kf][2] > ha[kf][3] ? ha[kf][2] : ha[kf][3];
                u32 c = a > b ? a : b;
                mx = mx > c ? mx : c;
            }
            if (!__any(mx == SENT)) break;
            const unsigned short* hp = hbuf + s0 * SLOT_ELEMS + hoff;
            #pragma unroll
            for (int kf = 0; kf < 16; ++kf) ha[kf] = llc_load16(hp + kf * 32);
            asm volatile("s_waitcnt vmcnt(0)" ::: "memory");
            __builtin_amdgcn_sched_barrier(0);
        }
        asm volatile("s_waitcnt vmcnt(0)" ::: "memory");   // drain xp prefetch
        __builtin_amdgcn_sched_barrier(0);

        // ---- sentinel-restore slot s2 (own 8B; dead: s0 full => s2 consumed) ----
        {
            u32x2 sv; sv[0] = SENT; sv[1] = SENT;
            llc_store8(hbuf + s2 * SLOT_ELEMS + poff, sv);
        }

        // ---- gates = xp + W_hh . h  (operand-swapped MFMA) ----
        f32x4 acc[4];
        #pragma unroll
        for (int cf = 0; cf < 4; ++cf) {
            acc[cf][0] = bf2f(xv[cf][0] & 0xFFFFu);
            acc[cf][1] = bf2f(xv[cf][0] >> 16);
            acc[cf][2] = bf2f(xv[cf][1] & 0xFFFFu);
            acc[cf][3] = bf2f(xv[cf][1] >> 16);
        }
        #pragma unroll
        for (int kf = 0; kf < 16; ++kf) {
            s16x8 h8 = __builtin_bit_cast(s16x8, ha[kf]);
            acc[0] = MFMA16(bw[0][kf], h8, acc[0], 0, 0, 0);
            acc[1] = MFMA16(bw[1][kf], h8, acc[1], 0, 0, 0);
            acc[2] = MFMA16(bw[2][kf], h8, acc[2], 0, 0, 0);
            acc[3] = MFMA16(bw[3][kf], h8, acc[3], 0, 0, 0);
        }

        // ---- cell update in-register ----
        f32x4 hvv;
        #pragma unroll
        for (int q = 0; q < 4; ++q) {
            float ig = sigm(acc[0][q]);
            float fg = sigm(acc[1][q]);
            float gg = tanhfast(acc[2][q]);
            float og = sigm(acc[3][q]);
            creg[q] = fg * creg[q] + ig * gg;
            hvv[q] = og * tanhfast(creg[q]);
        }

        // ---- publish h_{t+1}: ONE dwordx2, no shuffles ----
        {
            u32x2 pv;
            pv[0] = (u32)f2bf(hvv[0]) | ((u32)f2bf(hvv[1]) << 16);
            pv[1] = (u32)f2bf(hvv[2]) | ((u32)f2bf(hvv[3]) << 16);
            llc_store8(hbuf + s1 * SLOT_ELEMS + poff, pv);
        }

        // ---- out store: ONE dwordx4 (contiguous hid) ----
        *(f32x4*)(out + ((size_t)t * BATCH + b0 + jr) * HID + he0) = hvv;

        if (t == T_STEPS - 1) {
            *(f32x4*)(out + (size_t)T_STEPS * BATCH * HID
                          + (size_t)(b0 + jr) * HID + he0) = hvv;
            f32x4 cv; cv[0]=creg[0]; cv[1]=creg[1]; cv[2]=creg[2]; cv[3]=creg[3];
            *(f32x4*)(out + (size_t)T_STEPS * BATCH * HID + BATCH * HID
                          + (size_t)(b0 + jr) * HID + he0) = cv;
        } else {
            // issue next h loads FIRST (vmcnt(4) isolates them), then xp
            const unsigned short* hp = hbuf + s1 * SLOT_ELEMS + hoff;
            #pragma unroll
            for (int kf = 0; kf < 16; ++kf) ha[kf] = llc_load16(hp + kf * 32);
            const unsigned short* xq = xp + ((size_t)(t + 1) * BATCH + b0 + jr) * NG + he0;
            #pragma unroll
            for (int cf = 0; cf < 4; ++cf) xv[cf] = *(const u32x2*)(xq + cf * 512);
        }
    }
}

extern "C" void kernel_launch(void* const* d_in, const int* in_sizes, int n_in,
                              void* d_out, int out_size, void* d_ws, size_t ws_size,
                              hipStream_t stream) {
    const float* x   = (const float*)d_in[0];
    const float* h0  = (const float*)d_in[1];
    const float* c0  = (const float*)d_in[2];
    const float* Wih = (const float*)d_in[3];
    const float* Whh = (const float*)d_in[4];
    const float* bih = (const float*)d_in[5];
    const float* bhh = (const float*)d_in[6];
    float* out = (float*)d_out;

    char* ws = (char*)d_ws;
    unsigned short* hbuf = (unsigned short*)(ws + HBUF_OFF);
    unsigned short* xp   = (unsigned short*)(ws + XP_OFF);

    init_k<<<dim3(192), dim3(256), 0, stream>>>(h0, hbuf);
    xproj_k<<<dim3(512), dim3(256), 0, stream>>>(x, Wih, bih, bhh, xp);
    rec_k<<<dim3(64), dim3(64), 0, stream>>>(xp, Whh, c0, hbuf, out);
}

// Round 11
// 8363.434 us; speedup vs baseline: 1.1926x; 1.0010x over previous
//
#include <hip/hip_runtime.h>
#include <cstdint>
#include <cstddef>

#define T_STEPS 2048
#define BATCH   32
#define HID     512
#define NG      2048            // 4*HID gate rows

typedef __attribute__((ext_vector_type(8))) short        s16x8;
typedef __attribute__((ext_vector_type(4))) float        f32x4;
typedef __attribute__((ext_vector_type(4))) unsigned int u32x4;
typedef __attribute__((ext_vector_type(2))) unsigned int u32x2;
typedef unsigned int u32;

// ws layout: hbuf (3 slots x [32][512] bf16 = 96 KB), xp packed (256 MB)
// xp packed layout: [t][role(64)][clane(64)][8 u32] : lane's 4 cf-chunks contiguous.
#define SLOT_ELEMS (BATCH * HID)                 // 16384
#define HBUF_OFF   0
#define XP_OFF     (3 * SLOT_ELEMS * 2 + 4096)   // 102400
#define SENT 0xFFFFFFFFu

__device__ __forceinline__ unsigned short f2bf(float f) {
    u32 u = __builtin_bit_cast(u32, f);
    u += 0x7FFFu + ((u >> 16) & 1u);             // RTNE
    return (unsigned short)(u >> 16);
}
__device__ __forceinline__ float bf2f(u32 h) {   // bf16 in low 16 bits
    return __builtin_bit_cast(float, h << 16);
}
__device__ __forceinline__ float sigm(float x) {
    return __fdividef(1.0f, 1.0f + __expf(-x));
}
__device__ __forceinline__ float tanhfast(float x) {
    float xc = fminf(fmaxf(x, -15.0f), 15.0f);
    float e = __expf(2.0f * xc);
    return __fdividef(e - 1.0f, e + 1.0f);
}

// System-coherent exchange ops (LLC coherence point; proven live r2-r10).
// Loads NOT ready until an explicit s_waitcnt vmcnt.
__device__ __forceinline__ u32x4 llc_load16(const unsigned short* p) {
    u32x4 r;
    asm volatile("global_load_dwordx4 %0, %1, off sc0 sc1" : "=v"(r) : "v"(p) : "memory");
    return r;
}
__device__ __forceinline__ void llc_store8(unsigned short* p, u32x2 v) {
    asm volatile("global_store_dwordx2 %0, %1, off sc0 sc1" :: "v"(p), "v"(v) : "memory");
}

#define MFMA16 __builtin_amdgcn_mfma_f32_16x16x32_bf16

// ---------------- init: slot0 = h0 (bf16), slots 1,2 = sentinel ----------------
__global__ void init_k(const float* __restrict__ h0, unsigned short* __restrict__ hb) {
    int idx = blockIdx.x * 256 + threadIdx.x;          // grid 192 -> 49152
    if (idx < SLOT_ELEMS) hb[idx] = f2bf(h0[idx]);
    else                  hb[idx] = 0xFFFFu;           // sentinel halves
}

// ---------------- xproj: packed gate pre-projection ----------------
// xp[t][role][clane][cf] (u32x2 per cf) = (x @ Wih^T) + bih + bhh, laid out in
// the recurrence's per-lane consumption order (role = grp*32+w, clane = jr+kq*16).
__launch_bounds__(256, 1)
__global__ void xproj_k(const float* __restrict__ x, const float* __restrict__ Wih,
                        const float* __restrict__ bih, const float* __restrict__ bhh,
                        u32* __restrict__ xpw) {
    const int tid = threadIdx.x, lane = tid & 63, wv = tid >> 6;
    const int gblk = blockIdx.x & 31, tch = blockIdx.x >> 5;
    const int g0 = gblk * 64 + wv * 16;
    const int jr = lane & 15, kq = lane >> 4;

    __shared__ unsigned short xs[32][520];

    s16x8 aw[16];
    #pragma unroll
    for (int kf = 0; kf < 16; ++kf) {
        const float* s = Wih + (size_t)(g0 + jr) * 512 + kf * 32 + kq * 8;
        f32x4 v0 = *(const f32x4*)s, v1 = *(const f32x4*)(s + 4);
        s16x8 f;
        f[0]=(short)f2bf(v0[0]); f[1]=(short)f2bf(v0[1]); f[2]=(short)f2bf(v0[2]); f[3]=(short)f2bf(v0[3]);
        f[4]=(short)f2bf(v1[0]); f[5]=(short)f2bf(v1[1]); f[6]=(short)f2bf(v1[2]); f[7]=(short)f2bf(v1[3]);
        aw[kf] = f;
    }
    float bias[4];
    #pragma unroll
    for (int q = 0; q < 4; ++q) bias[q] = bih[g0 + kq*4 + q] + bhh[g0 + kq*4 + q];

    // packed-store geometry for this lane's outputs
    const int role0 = (gblk & 7) * 4 + wv;      // consumer role (group 0)
    const int cf    = gblk >> 3;                // gate type
    const int clane = jr + kq * 16;             // consumer lane

    const int lb = tid & 31, lk = (tid >> 5) * 64;
    const int t0 = tch * 128, t1 = t0 + 128;

    f32x4 pre[16];
    {
        const float* src = x + ((size_t)t0 * BATCH + lb) * 512 + lk;
        #pragma unroll
        for (int i = 0; i < 8; ++i) {
            pre[2*i]   = *(const f32x4*)(src + i * 8);
            pre[2*i+1] = *(const f32x4*)(src + i * 8 + 4);
        }
        #pragma unroll
        for (int i = 0; i < 8; ++i) {
            s16x8 f;
            f[0]=(short)f2bf(pre[2*i][0]);   f[1]=(short)f2bf(pre[2*i][1]);
            f[2]=(short)f2bf(pre[2*i][2]);   f[3]=(short)f2bf(pre[2*i][3]);
            f[4]=(short)f2bf(pre[2*i+1][0]); f[5]=(short)f2bf(pre[2*i+1][1]);
            f[6]=(short)f2bf(pre[2*i+1][2]); f[7]=(short)f2bf(pre[2*i+1][3]);
            *(s16x8*)&xs[lb][lk + i * 8] = f;
        }
    }
    __syncthreads();

    for (int t = t0; t < t1; ++t) {
        if (t + 1 < t1) {
            const float* src = x + ((size_t)(t+1) * BATCH + lb) * 512 + lk;
            #pragma unroll
            for (int i = 0; i < 8; ++i) {
                pre[2*i]   = *(const f32x4*)(src + i * 8);
                pre[2*i+1] = *(const f32x4*)(src + i * 8 + 4);
            }
        }
        f32x4 acc0 = {0,0,0,0}, acc1 = {0,0,0,0};
        #pragma unroll
        for (int kf = 0; kf < 16; ++kf) {
            s16x8 xb0 = *(const s16x8*)&xs[jr][kf * 32 + kq * 8];
            s16x8 xb1 = *(const s16x8*)&xs[16 + jr][kf * 32 + kq * 8];
            acc0 = MFMA16(aw[kf], xb0, acc0, 0, 0, 0);
            acc1 = MFMA16(aw[kf], xb1, acc1, 0, 0, 0);
        }
        // D: row = gate g0+kq*4+q, col = batch jr (acc0) / 16+jr (acc1).
        // Packed store: one u32x2 per (role, clane, cf).
        {
            u32x2 va, vb;
            va[0] = (u32)f2bf(acc0[0]+bias[0]) | ((u32)f2bf(acc0[1]+bias[1]) << 16);
            va[1] = (u32)f2bf(acc0[2]+bias[2]) | ((u32)f2bf(acc0[3]+bias[3]) << 16);
            vb[0] = (u32)f2bf(acc1[0]+bias[0]) | ((u32)f2bf(acc1[1]+bias[1]) << 16);
            vb[1] = (u32)f2bf(acc1[2]+bias[2]) | ((u32)f2bf(acc1[3]+bias[3]) << 16);
            size_t s0i = (((size_t)t * 64 + role0)      * 64 + clane) * 8 + cf * 2;
            size_t s1i = (((size_t)t * 64 + 32 + role0) * 64 + clane) * 8 + cf * 2;
            *(u32x2*)&xpw[s0i] = va;
            *(u32x2*)&xpw[s1i] = vb;
        }
        __syncthreads();
        if (t + 1 < t1) {
            #pragma unroll
            for (int i = 0; i < 8; ++i) {
                s16x8 f;
                f[0]=(short)f2bf(pre[2*i][0]);   f[1]=(short)f2bf(pre[2*i][1]);
                f[2]=(short)f2bf(pre[2*i][2]);   f[3]=(short)f2bf(pre[2*i][3]);
                f[4]=(short)f2bf(pre[2*i+1][0]); f[5]=(short)f2bf(pre[2*i+1][1]);
                f[6]=(short)f2bf(pre[2*i+1][2]); f[7]=(short)f2bf(pre[2*i+1][3]);
                *(s16x8*)&xs[lb][lk + i * 8] = f;
            }
        }
        __syncthreads();
    }
}

// ---------------- persistent recurrence: 64 WGs x 64 threads ----------
// r10 structure (operand-swapped MFMA, contiguous publish) + packed xp reads
// (2 x dwordx4 per lane) + 2-step-deep xp prefetch (named sets, unroll x2).
__launch_bounds__(64, 1)
__global__ void rec_k(const u32* __restrict__ xpw,
                      const float* __restrict__ Whh,
                      const float* __restrict__ c0,
                      unsigned short* __restrict__ hbuf,   // [3][32][512] bf16
                      float* __restrict__ out) {
    const int lane = threadIdx.x & 63;
    const int grp  = blockIdx.x >> 5;     // 0..1
    const int w    = blockIdx.x & 31;     // hid block
    const int b0   = grp * 16;
    const int jr   = lane & 15, kq = lane >> 4;
    const int role = grp * 32 + w;
    const int clane = jr + kq * 16;

    // weights as MFMA A-operand: Whh[cf*512 + w*16 + jr][k] (4x16 frags)
    s16x8 bw[4][16];
    #pragma unroll
    for (int cf = 0; cf < 4; ++cf) {
        #pragma unroll
        for (int kf = 0; kf < 16; ++kf) {
            const float* s = Whh + (size_t)(cf * 512 + w * 16 + jr) * 512 + kf * 32 + kq * 8;
            f32x4 v0 = *(const f32x4*)s, v1 = *(const f32x4*)(s + 4);
            s16x8 f;
            f[0]=(short)f2bf(v0[0]); f[1]=(short)f2bf(v0[1]); f[2]=(short)f2bf(v0[2]); f[3]=(short)f2bf(v0[3]);
            f[4]=(short)f2bf(v1[0]); f[5]=(short)f2bf(v1[1]); f[6]=(short)f2bf(v1[2]); f[7]=(short)f2bf(v1[3]);
            bw[cf][kf] = f;
        }
    }

    // cell ownership: batch b0+jr, hid he0..he0+3 (contiguous)
    const int he0 = w * 16 + kq * 4;
    float creg[4];
    {
        f32x4 c4 = *(const f32x4*)(c0 + (size_t)(b0 + jr) * HID + he0);
        creg[0]=c4[0]; creg[1]=c4[1]; creg[2]=c4[2]; creg[3]=c4[3];
    }

    const int hoff = (b0 + jr) * HID + kq * 8;   // consume-frag offset
    const int poff = (b0 + jr) * HID + he0;      // publish offset (8B contiguous)
    const size_t xbase = ((size_t)role * 64 + clane) * 8;   // u32 units, + t*64*64*8

    u32x4 ha[16];
    {   // prologue: h slot0 loads, then xp t=0 (set A) and t=1 (set B)
        const unsigned short* hp = hbuf + hoff;
        #pragma unroll
        for (int kf = 0; kf < 16; ++kf) ha[kf] = llc_load16(hp + kf * 32);
    }
    u32x4 xa_lo, xa_hi, xb_lo, xb_hi;
    {
        const u32* xq0 = xpw + ((size_t)0 * 4096 * 8 + xbase);
        xa_lo = *(const u32x4*)xq0; xa_hi = *(const u32x4*)(xq0 + 4);
        const u32* xq1 = xpw + ((size_t)1 * 4096 * 8 + xbase);
        xb_lo = *(const u32x4*)xq1; xb_hi = *(const u32x4*)(xq1 + 4);
    }

// One recurrence step. XV_LO/XV_HI: this step's xp registers (refilled for t+2).
#define STEP(T_IDX, XV_LO, XV_HI)                                               \
    {                                                                           \
        const int t_ = (T_IDX);                                                 \
        const int s0 = t_ % 3, s1 = (t_ + 1) % 3, s2 = (t_ + 2) % 3;            \
        /* entry: wait stores + h loads + current xv; leave newest refill(2) */ \
        asm volatile("s_waitcnt vmcnt(2)" ::: "memory");                        \
        __builtin_amdgcn_sched_barrier(0);                                      \
        while (true) {                                                          \
            u32 mx = 0;                                                         \
            _Pragma("unroll")                                                   \
            for (int kf = 0; kf < 16; ++kf) {                                   \
                u32 a_ = ha[kf][0] > ha[kf][1] ? ha[kf][0] : ha[kf][1];         \
                u32 b_ = ha[kf][2] > ha[kf][3] ? ha[kf][2] : ha[kf][3];         \
                u32 c_ = a_ > b_ ? a_ : b_;                                     \
                mx = mx > c_ ? mx : c_;                                         \
            }                                                                   \
            if (!__any(mx == SENT)) break;                                      \
            const unsigned short* hp_ = hbuf + s0 * SLOT_ELEMS + hoff;          \
            _Pragma("unroll")                                                   \
            for (int kf = 0; kf < 16; ++kf) ha[kf] = llc_load16(hp_ + kf * 32); \
            asm volatile("s_waitcnt vmcnt(0)" ::: "memory");                    \
            __builtin_amdgcn_sched_barrier(0);                                  \
        }                                                                       \
        /* sentinel-restore slot s2 (own 8B; dead by induction) */              \
        {                                                                       \
            u32x2 sv; sv[0] = SENT; sv[1] = SENT;                               \
            llc_store8(hbuf + s2 * SLOT_ELEMS + poff, sv);                      \
        }                                                                       \
        f32x4 acc[4];                                                           \
        acc[0][0]=bf2f(XV_LO[0]&0xFFFFu); acc[0][1]=bf2f(XV_LO[0]>>16);         \
        acc[0][2]=bf2f(XV_LO[1]&0xFFFFu); acc[0][3]=bf2f(XV_LO[1]>>16);         \
        acc[1][0]=bf2f(XV_LO[2]&0xFFFFu); acc[1][1]=bf2f(XV_LO[2]>>16);         \
        acc[1][2]=bf2f(XV_LO[3]&0xFFFFu); acc[1][3]=bf2f(XV_LO[3]>>16);         \
        acc[2][0]=bf2f(XV_HI[0]&0xFFFFu); acc[2][1]=bf2f(XV_HI[0]>>16);         \
        acc[2][2]=bf2f(XV_HI[1]&0xFFFFu); acc[2][3]=bf2f(XV_HI[1]>>16);         \
        acc[3][0]=bf2f(XV_HI[2]&0xFFFFu); acc[3][1]=bf2f(XV_HI[2]>>16);         \
        acc[3][2]=bf2f(XV_HI[3]&0xFFFFu); acc[3][3]=bf2f(XV_HI[3]>>16);         \
        _Pragma("unroll")                                                       \
        for (int kf = 0; kf < 16; ++kf) {                                       \
            s16x8 h8 = __builtin_bit_cast(s16x8, ha[kf]);                       \
            acc[0] = MFMA16(bw[0][kf], h8, acc[0], 0, 0, 0);                    \
            acc[1] = MFMA16(bw[1][kf], h8, acc[1], 0, 0, 0);                    \
            acc[2] = MFMA16(bw[2][kf], h8, acc[2], 0, 0, 0);                    \
            acc[3] = MFMA16(bw[3][kf], h8, acc[3], 0, 0, 0);                    \
        }                                                                       \
        f32x4 hvv;                                                              \
        _Pragma("unroll")                                                       \
        for (int q = 0; q < 4; ++q) {                                           \
            float ig = sigm(acc[0][q]);                                         \
            float fg = sigm(acc[1][q]);                                         \
            float gg = tanhfast(acc[2][q]);                                     \
            float og = sigm(acc[3][q]);                                         \
            creg[q] = fg * creg[q] + ig * gg;                                   \
            hvv[q] = og * tanhfast(creg[q]);                                    \
        }                                                                       \
        /* publish h_{t+1}: one dwordx2 */                                      \
        {                                                                       \
            u32x2 pv;                                                           \
            pv[0] = (u32)f2bf(hvv[0]) | ((u32)f2bf(hvv[1]) << 16);              \
            pv[1] = (u32)f2bf(hvv[2]) | ((u32)f2bf(hvv[3]) << 16);              \
            llc_store8(hbuf + s1 * SLOT_ELEMS + poff, pv);                      \
        }                                                                       \
        if (t_ == T_STEPS - 1) {                                                \
            *(f32x4*)(out + ((size_t)t_ * BATCH + b0 + jr) * HID + he0) = hvv;  \
            *(f32x4*)(out + (size_t)T_STEPS * BATCH * HID                       \
                          + (size_t)(b0 + jr) * HID + he0) = hvv;               \
            f32x4 cv; cv[0]=creg[0]; cv[1]=creg[1]; cv[2]=creg[2]; cv[3]=creg[3];\
            *(f32x4*)(out + (size_t)T_STEPS * BATCH * HID + BATCH * HID         \
                          + (size_t)(b0 + jr) * HID + he0) = cv;                \
        } else {                                                                \
            /* issue next h loads FIRST, then out, then xp refill (newest) */   \
            const unsigned short* hp_ = hbuf + s1 * SLOT_ELEMS + hoff;          \
            _Pragma("unroll")                                                   \
            for (int kf = 0; kf < 16; ++kf) ha[kf] = llc_load16(hp_ + kf * 32); \
            *(f32x4*)(out + ((size_t)t_ * BATCH + b0 + jr) * HID + he0) = hvv;  \
            int tr_ = (t_ + 2 < T_STEPS) ? (t_ + 2) : (T_STEPS - 1);            \
            const u32* xq_ = xpw + ((size_t)tr_ * 4096 * 8 + xbase);            \
            XV_LO = *(const u32x4*)xq_;                                         \
            XV_HI = *(const u32x4*)(xq_ + 4);                                   \
        }                                                                       \
    }

    for (int t = 0; t < T_STEPS; t += 2) {
        STEP(t,     xa_lo, xa_hi);
        STEP(t + 1, xb_lo, xb_hi);
    }
#undef STEP
}

extern "C" void kernel_launch(void* const* d_in, const int* in_sizes, int n_in,
                              void* d_out, int out_size, void* d_ws, size_t ws_size,
                              hipStream_t stream) {
    const float* x   = (const float*)d_in[0];
    const float* h0  = (const float*)d_in[1];
    const float* c0  = (const float*)d_in[2];
    const float* Wih = (const float*)d_in[3];
    const float* Whh = (const float*)d_in[4];
    const float* bih = (const float*)d_in[5];
    const float* bhh = (const float*)d_in[6];
    float* out = (float*)d_out;

    char* ws = (char*)d_ws;
    unsigned short* hbuf = (unsigned short*)(ws + HBUF_OFF);
    u32*            xpw  = (u32*)(ws + XP_OFF);

    init_k<<<dim3(192), dim3(256), 0, stream>>>(h0, hbuf);
    xproj_k<<<dim3(512), dim3(256), 0, stream>>>(x, Wih, bih, bhh, xpw);
    rec_k<<<dim3(64), dim3(64), 0, stream>>>(xpw, Whh, c0, hbuf, out);
}

// Round 12
// 8007.325 us; speedup vs baseline: 1.2456x; 1.0445x over previous
//
#include <hip/hip_runtime.h>
#include <cstdint>
#include <cstddef>

#define T_STEPS 2048
#define BATCH   32
#define HID     512
#define NG      2048            // 4*HID gate rows

typedef __attribute__((ext_vector_type(8))) short        s16x8;
typedef __attribute__((ext_vector_type(4))) float        f32x4;
typedef __attribute__((ext_vector_type(4))) unsigned int u32x4;
typedef __attribute__((ext_vector_type(2))) unsigned int u32x2;
typedef unsigned int u32;

// ws layout: tok (4 KB: 2 groups x 32 u32, 128B lines), hbuf (3x32KB... 96 KB),
// xp packed (256 MB). xp layout: [t][role(64)][clane(64)][8 u32].
#define TOK_OFF    0
#define HBUF_OFF   4096
#define SLOT_ELEMS (BATCH * HID)                 // 16384
#define XP_OFF     (HBUF_OFF + 3 * SLOT_ELEMS * 2)   // 102400

__device__ __forceinline__ unsigned short f2bf(float f) {
    u32 u = __builtin_bit_cast(u32, f);
    u += 0x7FFFu + ((u >> 16) & 1u);             // RTNE
    return (unsigned short)(u >> 16);
}
__device__ __forceinline__ float bf2f(u32 h) {   // bf16 in low 16 bits
    return __builtin_bit_cast(float, h << 16);
}
__device__ __forceinline__ float sigm(float x) {
    return __fdividef(1.0f, 1.0f + __expf(-x));
}
__device__ __forceinline__ float tanhfast(float x) {
    float xc = fminf(fmaxf(x, -15.0f), 15.0f);
    float e = __expf(2.0f * xc);
    return __fdividef(e - 1.0f, e + 1.0f);
}

// System-coherent ops (MALL coherence point; proven live r2-r11).
// Loads NOT ready until an explicit s_waitcnt vmcnt.
__device__ __forceinline__ u32x4 llc_load16(const unsigned short* p) {
    u32x4 r;
    asm volatile("global_load_dwordx4 %0, %1, off sc0 sc1" : "=v"(r) : "v"(p) : "memory");
    return r;
}
__device__ __forceinline__ void llc_store8(unsigned short* p, u32x2 v) {
    asm volatile("global_store_dwordx2 %0, %1, off sc0 sc1" :: "v"(p), "v"(v) : "memory");
}

#define MFMA16 __builtin_amdgcn_mfma_f32_16x16x32_bf16

// ---------------- init: slot0 = h0 (bf16), tokens = 0 ----------------
__global__ void init_k(const float* __restrict__ h0, unsigned short* __restrict__ hb,
                       u32* __restrict__ tok) {
    int idx = blockIdx.x * 256 + threadIdx.x;          // grid 64 -> 16384
    hb[idx] = f2bf(h0[idx]);
    if (blockIdx.x == 0 && threadIdx.x < 64) tok[threadIdx.x] = 0;
}

// ---------------- xproj: packed gate pre-projection (r11-proven) ----------------
// xp[t][role][clane][cf] (u32x2 per cf) = (x @ Wih^T) + bih + bhh in the
// recurrence's per-lane consumption order (role = grp*32+w, clane = jr+kq*16).
__launch_bounds__(256, 1)
__global__ void xproj_k(const float* __restrict__ x, const float* __restrict__ Wih,
                        const float* __restrict__ bih, const float* __restrict__ bhh,
                        u32* __restrict__ xpw) {
    const int tid = threadIdx.x, lane = tid & 63, wv = tid >> 6;
    const int gblk = blockIdx.x & 31, tch = blockIdx.x >> 5;
    const int g0 = gblk * 64 + wv * 16;
    const int jr = lane & 15, kq = lane >> 4;

    __shared__ unsigned short xs[32][520];

    s16x8 aw[16];
    #pragma unroll
    for (int kf = 0; kf < 16; ++kf) {
        const float* s = Wih + (size_t)(g0 + jr) * 512 + kf * 32 + kq * 8;
        f32x4 v0 = *(const f32x4*)s, v1 = *(const f32x4*)(s + 4);
        s16x8 f;
        f[0]=(short)f2bf(v0[0]); f[1]=(short)f2bf(v0[1]); f[2]=(short)f2bf(v0[2]); f[3]=(short)f2bf(v0[3]);
        f[4]=(short)f2bf(v1[0]); f[5]=(short)f2bf(v1[1]); f[6]=(short)f2bf(v1[2]); f[7]=(short)f2bf(v1[3]);
        aw[kf] = f;
    }
    float bias[4];
    #pragma unroll
    for (int q = 0; q < 4; ++q) bias[q] = bih[g0 + kq*4 + q] + bhh[g0 + kq*4 + q];

    const int role0 = (gblk & 7) * 4 + wv;      // consumer role (group 0)
    const int cf    = gblk >> 3;                // gate type
    const int clane = jr + kq * 16;             // consumer lane

    const int lb = tid & 31, lk = (tid >> 5) * 64;
    const int t0 = tch * 128, t1 = t0 + 128;

    f32x4 pre[16];
    {
        const float* src = x + ((size_t)t0 * BATCH + lb) * 512 + lk;
        #pragma unroll
        for (int i = 0; i < 8; ++i) {
            pre[2*i]   = *(const f32x4*)(src + i * 8);
            pre[2*i+1] = *(const f32x4*)(src + i * 8 + 4);
        }
        #pragma unroll
        for (int i = 0; i < 8; ++i) {
            s16x8 f;
            f[0]=(short)f2bf(pre[2*i][0]);   f[1]=(short)f2bf(pre[2*i][1]);
            f[2]=(short)f2bf(pre[2*i][2]);   f[3]=(short)f2bf(pre[2*i][3]);
            f[4]=(short)f2bf(pre[2*i+1][0]); f[5]=(short)f2bf(pre[2*i+1][1]);
            f[6]=(short)f2bf(pre[2*i+1][2]); f[7]=(short)f2bf(pre[2*i+1][3]);
            *(s16x8*)&xs[lb][lk + i * 8] = f;
        }
    }
    __syncthreads();

    for (int t = t0; t < t1; ++t) {
        if (t + 1 < t1) {
            const float* src = x + ((size_t)(t+1) * BATCH + lb) * 512 + lk;
            #pragma unroll
            for (int i = 0; i < 8; ++i) {
                pre[2*i]   = *(const f32x4*)(src + i * 8);
                pre[2*i+1] = *(const f32x4*)(src + i * 8 + 4);
            }
        }
        f32x4 acc0 = {0,0,0,0}, acc1 = {0,0,0,0};
        #pragma unroll
        for (int kf = 0; kf < 16; ++kf) {
            s16x8 xb0 = *(const s16x8*)&xs[jr][kf * 32 + kq * 8];
            s16x8 xb1 = *(const s16x8*)&xs[16 + jr][kf * 32 + kq * 8];
            acc0 = MFMA16(aw[kf], xb0, acc0, 0, 0, 0);
            acc1 = MFMA16(aw[kf], xb1, acc1, 0, 0, 0);
        }
        {
            u32x2 va, vb;
            va[0] = (u32)f2bf(acc0[0]+bias[0]) | ((u32)f2bf(acc0[1]+bias[1]) << 16);
            va[1] = (u32)f2bf(acc0[2]+bias[2]) | ((u32)f2bf(acc0[3]+bias[3]) << 16);
            vb[0] = (u32)f2bf(acc1[0]+bias[0]) | ((u32)f2bf(acc1[1]+bias[1]) << 16);
            vb[1] = (u32)f2bf(acc1[2]+bias[2]) | ((u32)f2bf(acc1[3]+bias[3]) << 16);
            size_t s0i = (((size_t)t * 64 + role0)      * 64 + clane) * 8 + cf * 2;
            size_t s1i = (((size_t)t * 64 + 32 + role0) * 64 + clane) * 8 + cf * 2;
            *(u32x2*)&xpw[s0i] = va;
            *(u32x2*)&xpw[s1i] = vb;
        }
        __syncthreads();
        if (t + 1 < t1) {
            #pragma unroll
            for (int i = 0; i < 8; ++i) {
                s16x8 f;
                f[0]=(short)f2bf(pre[2*i][0]);   f[1]=(short)f2bf(pre[2*i][1]);
                f[2]=(short)f2bf(pre[2*i][2]);   f[3]=(short)f2bf(pre[2*i][3]);
                f[4]=(short)f2bf(pre[2*i+1][0]); f[5]=(short)f2bf(pre[2*i+1][1]);
                f[6]=(short)f2bf(pre[2*i+1][2]); f[7]=(short)f2bf(pre[2*i+1][3]);
                *(s16x8*)&xs[lb][lk + i * 8] = f;
            }
        }
        __syncthreads();
    }
}

// ---------------- persistent recurrence: 64 WGs x 64 threads, token protocol --
// r10/r11 geometry (operand-swapped MFMA, contiguous 8B publish). Readiness via
// per-producer monotone step tokens in ONE 128B line per group:
//   producer: publish data -> vmcnt(0) ack -> token store (t+1)
//   consumer: poll 1 line until __all(tok >= t) -> bulk-read slot ONCE.
// MALL serialization: token visible => data visible (ack'd before token issued).
__launch_bounds__(64, 1)
__global__ void rec_k(const u32* __restrict__ xpw,
                      const float* __restrict__ Whh,
                      const float* __restrict__ c0,
                      unsigned short* __restrict__ hbuf,   // [3][32][512] bf16
                      u32* __restrict__ tok,               // [2][32] (128B lines)
                      float* __restrict__ out) {
    const int lane = threadIdx.x & 63;
    const int grp  = blockIdx.x >> 5;     // 0..1
    const int w    = blockIdx.x & 31;     // hid block
    const int b0   = grp * 16;
    const int jr   = lane & 15, kq = lane >> 4;
    const int role = grp * 32 + w;
    const int clane = jr + kq * 16;

    // weights as MFMA A-operand: Whh[cf*512 + w*16 + jr][k] (4x16 frags)
    s16x8 bw[4][16];
    #pragma unroll
    for (int cf = 0; cf < 4; ++cf) {
        #pragma unroll
        for (int kf = 0; kf < 16; ++kf) {
            const float* s = Whh + (size_t)(cf * 512 + w * 16 + jr) * 512 + kf * 32 + kq * 8;
            f32x4 v0 = *(const f32x4*)s, v1 = *(const f32x4*)(s + 4);
            s16x8 f;
            f[0]=(short)f2bf(v0[0]); f[1]=(short)f2bf(v0[1]); f[2]=(short)f2bf(v0[2]); f[3]=(short)f2bf(v0[3]);
            f[4]=(short)f2bf(v1[0]); f[5]=(short)f2bf(v1[1]); f[6]=(short)f2bf(v1[2]); f[7]=(short)f2bf(v1[3]);
            bw[cf][kf] = f;
        }
    }

    // cell ownership: batch b0+jr, hid he0..he0+3 (contiguous)
    const int he0 = w * 16 + kq * 4;
    float creg[4];
    {
        f32x4 c4 = *(const f32x4*)(c0 + (size_t)(b0 + jr) * HID + he0);
        creg[0]=c4[0]; creg[1]=c4[1]; creg[2]=c4[2]; creg[3]=c4[3];
    }

    const int hoff = (b0 + jr) * HID + kq * 8;   // consume-frag offset
    const int poff = (b0 + jr) * HID + he0;      // publish offset (8B contiguous)
    const size_t xbase = ((size_t)role * 64 + clane) * 8;   // u32 units

    const u32* tpoll = tok + grp * 32 + (lane & 31);
    u32*       tmine = tok + grp * 32 + w;

    u32 tokv = 0;

    for (int t = 0; t < T_STEPS; ++t) {
        // ---- detect: poll the group's single token line until all >= t ----
        if (t > 0) {
            asm volatile("s_waitcnt vmcnt(0)" ::: "memory");   // warm tokv landed
            __builtin_amdgcn_sched_barrier(0);
            while (!__all(tokv >= (u32)t)) {
                asm volatile("global_load_dword %0, %1, off sc0 sc1"
                             : "=v"(tokv) : "v"(tpoll) : "memory");
                asm volatile("s_waitcnt vmcnt(0)" ::: "memory");
                __builtin_amdgcn_sched_barrier(0);
            }
        }

        // ---- bulk h read (ONCE, guaranteed fresh) + xp read, in parallel ----
        u32x4 ha[16];
        {
            const unsigned short* hp = hbuf + (t % 3) * SLOT_ELEMS + hoff;
            #pragma unroll
            for (int kf = 0; kf < 16; ++kf) ha[kf] = llc_load16(hp + kf * 32);
        }
        const u32* xq = xpw + ((size_t)t * 4096 * 8 + xbase);
        u32x4 xlo = *(const u32x4*)xq;
        u32x4 xhi = *(const u32x4*)(xq + 4);
        asm volatile("s_waitcnt vmcnt(0)" ::: "memory");
        __builtin_amdgcn_sched_barrier(0);

        // ---- gates = xp + W_hh . h (operand-swapped MFMA) ----
        f32x4 acc[4];
        acc[0][0]=bf2f(xlo[0]&0xFFFFu); acc[0][1]=bf2f(xlo[0]>>16);
        acc[0][2]=bf2f(xlo[1]&0xFFFFu); acc[0][3]=bf2f(xlo[1]>>16);
        acc[1][0]=bf2f(xlo[2]&0xFFFFu); acc[1][1]=bf2f(xlo[2]>>16);
        acc[1][2]=bf2f(xlo[3]&0xFFFFu); acc[1][3]=bf2f(xlo[3]>>16);
        acc[2][0]=bf2f(xhi[0]&0xFFFFu); acc[2][1]=bf2f(xhi[0]>>16);
        acc[2][2]=bf2f(xhi[1]&0xFFFFu); acc[2][3]=bf2f(xhi[1]>>16);
        acc[3][0]=bf2f(xhi[2]&0xFFFFu); acc[3][1]=bf2f(xhi[2]>>16);
        acc[3][2]=bf2f(xhi[3]&0xFFFFu); acc[3][3]=bf2f(xhi[3]>>16);
        #pragma unroll
        for (int kf = 0; kf < 16; ++kf) {
            s16x8 h8 = __builtin_bit_cast(s16x8, ha[kf]);
            acc[0] = MFMA16(bw[0][kf], h8, acc[0], 0, 0, 0);
            acc[1] = MFMA16(bw[1][kf], h8, acc[1], 0, 0, 0);
            acc[2] = MFMA16(bw[2][kf], h8, acc[2], 0, 0, 0);
            acc[3] = MFMA16(bw[3][kf], h8, acc[3], 0, 0, 0);
        }

        // ---- cell update in-register ----
        f32x4 hvv;
        #pragma unroll
        for (int q = 0; q < 4; ++q) {
            float ig = sigm(acc[0][q]);
            float fg = sigm(acc[1][q]);
            float gg = tanhfast(acc[2][q]);
            float og = sigm(acc[3][q]);
            creg[q] = fg * creg[q] + ig * gg;
            hvv[q] = og * tanhfast(creg[q]);
        }

        if (t < T_STEPS - 1) {
            // ---- publish -> ack -> token (release via MALL serialization) ----
            u32x2 pv;
            pv[0] = (u32)f2bf(hvv[0]) | ((u32)f2bf(hvv[1]) << 16);
            pv[1] = (u32)f2bf(hvv[2]) | ((u32)f2bf(hvv[3]) << 16);
            llc_store8(hbuf + ((t + 1) % 3) * SLOT_ELEMS + poff, pv);
            asm volatile("s_waitcnt vmcnt(0)" ::: "memory");   // data at MALL
            __builtin_amdgcn_sched_barrier(0);
            if (lane == 0)
                asm volatile("global_store_dword %0, %1, off sc0 sc1"
                             :: "v"(tmine), "v"((u32)(t + 1)) : "memory");
            // warm poll for next step
            asm volatile("global_load_dword %0, %1, off sc0 sc1"
                         : "=v"(tokv) : "v"(tpoll) : "memory");
        }

        // ---- out store (normal cached, off sync path) ----
        *(f32x4*)(out + ((size_t)t * BATCH + b0 + jr) * HID + he0) = hvv;
        if (t == T_STEPS - 1) {
            *(f32x4*)(out + (size_t)T_STEPS * BATCH * HID
                          + (size_t)(b0 + jr) * HID + he0) = hvv;
            f32x4 cv; cv[0]=creg[0]; cv[1]=creg[1]; cv[2]=creg[2]; cv[3]=creg[3];
            *(f32x4*)(out + (size_t)T_STEPS * BATCH * HID + BATCH * HID
                          + (size_t)(b0 + jr) * HID + he0) = cv;
        }
    }
}

extern "C" void kernel_launch(void* const* d_in, const int* in_sizes, int n_in,
                              void* d_out, int out_size, void* d_ws, size_t ws_size,
                              hipStream_t stream) {
    const float* x   = (const float*)d_in[0];
    const float* h0  = (const float*)d_in[1];
    const float* c0  = (const float*)d_in[2];
    const float* Wih = (const float*)d_in[3];
    const float* Whh = (const float*)d_in[4];
    const float* bih = (const float*)d_in[5];
    const float* bhh = (const float*)d_in[6];
    float* out = (float*)d_out;

    char* ws = (char*)d_ws;
    u32*            tokp = (u32*)(ws + TOK_OFF);
    unsigned short* hbuf = (unsigned short*)(ws + HBUF_OFF);
    u32*            xpw  = (u32*)(ws + XP_OFF);

    init_k<<<dim3(64), dim3(256), 0, stream>>>(h0, hbuf, tokp);
    xproj_k<<<dim3(512), dim3(256), 0, stream>>>(x, Wih, bih, bhh, xpw);
    rec_k<<<dim3(64), dim3(64), 0, stream>>>(xpw, Whh, c0, hbuf, tokp, out);
}